// Round 5
// baseline (3377.459 us; speedup 1.0000x reference)
//
#include <hip/hip_runtime.h>
#include <stdint.h>
#include <stddef.h>

#define Bsz 1024
#define Tsz 512
#define Dsz 256
#define Hsz 256
#define SLAB 24576   // bytes per (t, bgroup16) slab: [r 8K][n 8K][a 8K], wave-grouped

typedef __bf16 bf16;
typedef __attribute__((ext_vector_type(8))) __bf16 bf16x8;
typedef __attribute__((ext_vector_type(4))) float f32x4;

__device__ __forceinline__ float bf2f(bf16 v) { return (float)v; }
__device__ __forceinline__ float sigm(float x) {
  return __builtin_amdgcn_rcpf(1.f + exp2f(-1.4426950408889634f * x));
}
__device__ __forceinline__ float bflo(uint32_t v) {
  union { uint32_t u; float f; } c; c.u = v << 16; return c.f;
}
__device__ __forceinline__ float bfhi(uint32_t v) {
  union { uint32_t u; float f; } c; c.u = v & 0xffff0000u; return c.f;
}

// ============ repack Wx(R,N), Wh(R,N) into MFMA-fragment-major bf16 ============
__global__ __launch_bounds__(256) void k_repack(
    const float* __restrict__ Wx, const float* __restrict__ Wh,
    bf16* __restrict__ wxf, bf16* __restrict__ whf) {
  int g = blockIdx.x * 256 + threadIdx.x;   // 32768 total
  int gg = g & 16383;
  int lr = gg & 15, lq = (gg >> 4) & 3, kp = (gg >> 6) & 7, tile = gg >> 9;
  int row = (tile < 16) ? (tile * 16 + lr) : (512 + (tile - 16) * 16 + lr);
  const float* s;
  bf16* d;
  if (g < 16384) { s = Wx + row * 256 + kp * 32 + lq * 8; d = wxf + gg * 8; }
  else           { s = Wh + row * 256 + kp * 32 + lq * 8; d = whf + gg * 8; }
  #pragma unroll
  for (int e = 0; e < 8; ++e) d[e] = (bf16)s[e];
}

// ==== Wc = Wa_h @ Wh_I ; Wp = Wa_i @ Wx_I ; c0 = ba + Wa_h@bh_I + Wa_i@bx_I ====
__global__ __launch_bounds__(256) void k_wc(
    const float* __restrict__ Wa, const float* __restrict__ Wh,
    const float* __restrict__ Wx, const float* __restrict__ bh,
    const float* __restrict__ bx, const float* __restrict__ ba,
    bf16* __restrict__ wcf, bf16* __restrict__ wxf, float* __restrict__ c0) {
  __shared__ float red[256];
  int n = blockIdx.x, k = threadIdx.x;
  float accC = 0.f, accP = 0.f;
  for (int m = 0; m < 256; ++m) {
    accC += Wa[n * 512 + 256 + m] * Wh[(256 + m) * 256 + k];
    accP += Wa[n * 512 + m]       * Wx[(256 + m) * 256 + k];
  }
  int kp = k >> 5, lq = (k >> 3) & 3, e = k & 7;
  int ti = n >> 4, lr = n & 15;
  wcf[(ti * 8 + kp) * 512 + lq * 128 + lr * 8 + e] = (bf16)accC;
  wxf[(((32 + ti) * 8) + kp) * 512 + lq * 128 + lr * 8 + e] = (bf16)accP;
  red[k] = Wa[n * 512 + 256 + k] * bh[256 + k] + Wa[n * 512 + k] * bx[256 + k];
  __syncthreads();
  for (int s = 128; s > 0; s >>= 1) {
    if (k < s) red[k] += red[k + s];
    __syncthreads();
  }
  if (k == 0) c0[n] = ba[n] + red[0];
}

// ============ phase 1: slab <- [x@WxR^T+bxr+bhr | x@WxN^T+bxn | x@Wp^T+c0] ======
// 512 thr / 8 waves; wave w computes t = tch*16 + w*2 + {0,1}; 16 batch rows.
__global__ __launch_bounds__(512, 4) void k_phase1(
    const float* __restrict__ x, const bf16* __restrict__ wxf,
    const float* __restrict__ bx, const float* __restrict__ bh,
    const float* __restrict__ c0, bf16* __restrict__ gx, int t0) {
  int tid = threadIdx.x;
  int w = tid >> 6, l = tid & 63, lr = l & 15, lq = l >> 4;
  int bg = blockIdx.x, b0 = bg << 4;
  int tch = blockIdx.y;

  bf16x8 Am[2][8];
  #pragma unroll
  for (int m = 0; m < 2; ++m) {
    int tglob = t0 + tch * 16 + w * 2 + m;
    const float* xp = x + ((size_t)(b0 + lr) * Tsz + tglob) * Dsz + lq * 8;
    #pragma unroll
    for (int kk = 0; kk < 8; ++kk) {
      float4 f0 = *(const float4*)(xp + kk * 32);
      float4 f1 = *(const float4*)(xp + kk * 32 + 4);
      bf16x8 a;
      a[0] = (bf16)f0.x; a[1] = (bf16)f0.y; a[2] = (bf16)f0.z; a[3] = (bf16)f0.w;
      a[4] = (bf16)f1.x; a[5] = (bf16)f1.y; a[6] = (bf16)f1.z; a[7] = (bf16)f1.w;
      Am[m][kk] = a;
    }
  }
  const bf16* bsrc = wxf + lq * 128 + lr * 8;
  #pragma unroll 1
  for (int ct = 0; ct < 48; ++ct) {
    float bias;
    if (ct < 16)      { int r = ct * 16 + lr;              bias = bx[r] + bh[r]; }
    else if (ct < 32) { int r = 512 + (ct - 16) * 16 + lr; bias = bx[r]; }
    else              bias = c0[(ct - 32) * 16 + lr];
    f32x4 acc[2];
    #pragma unroll
    for (int m = 0; m < 2; ++m)
      #pragma unroll
      for (int e = 0; e < 4; ++e) acc[m][e] = bias;
    #pragma unroll
    for (int kk = 0; kk < 8; ++kk) {
      bf16x8 Bf = *(const bf16x8*)(bsrc + (size_t)(ct * 8 + kk) * 512);
      acc[0] = __builtin_amdgcn_mfma_f32_16x16x32_bf16(Am[0][kk], Bf, acc[0], 0, 0, 0);
      acc[1] = __builtin_amdgcn_mfma_f32_16x16x32_bf16(Am[1][kk], Bf, acc[1], 0, 0, 0);
    }
    int region = ct >> 4, rct = ct & 15;
    int off = region * 8192 + (rct >> 2) * 2048 + lq * 512 + lr * 32 + (rct & 3) * 8;
    #pragma unroll
    for (int m = 0; m < 2; ++m) {
      int tl = tch * 16 + w * 2 + m;
      union { bf16 v[4]; uint2 u; } p;
      #pragma unroll
      for (int j = 0; j < 4; ++j) p.v[j] = (bf16)acc[m][j];
      *(uint2*)((char*)gx + ((size_t)tl * 64 + bg) * SLAB + off) = p.u;
    }
  }
}

// ============ phase 2: scan; ALL weights (R,N,C) register-resident ============
// 256 thr / 4 waves, 1 wave/SIMD (512-reg budget). Wave w owns cols w*64..+63.
__global__ __launch_bounds__(256, 1) void k_phase2(
    const bf16* __restrict__ gx, const bf16* __restrict__ whf,
    const bf16* __restrict__ wcf, const float* __restrict__ bh,
    float* __restrict__ out, float* __restrict__ hstate, int t0, int TC) {
  __shared__ char hb[2][8192];   // h bf16 A-frag layout, double-buffered
  int tid = threadIdx.x;
  int w = tid >> 6, l = tid & 63, lr = l & 15, lq = l >> 4;
  int bg = blockIdx.x, b0 = bg << 4;
  int laneoff = lq * 128 + lr * 8;

  // 96 weight fragments -> unified RF (B-operands, AGPR-eligible)
  bf16x8 wR[4][8], wN[4][8], wC[4][8];
  #pragma unroll
  for (int i = 0; i < 4; ++i)
    #pragma unroll
    for (int k = 0; k < 8; ++k) {
      wR[i][k] = *(const bf16x8*)(whf + (size_t)((w * 4 + i) * 8 + k) * 512 + laneoff);
      wN[i][k] = *(const bf16x8*)(whf + (size_t)((16 + w * 4 + i) * 8 + k) * 512 + laneoff);
      wC[i][k] = *(const bf16x8*)(wcf + (size_t)((w * 4 + i) * 8 + k) * 512 + laneoff);
    }
  float bN[4];
  #pragma unroll
  for (int i = 0; i < 4; ++i) bN[i] = bh[512 + (w * 4 + i) * 16 + lr];

  float h[4][4];
  #pragma unroll
  for (int i = 0; i < 4; ++i) {
    int col = (w * 4 + i) * 16 + lr;
    #pragma unroll
    for (int j = 0; j < 4; ++j)
      h[i][j] = (t0 == 0) ? 0.f : hstate[(size_t)(b0 + lq * 4 + j) * Hsz + col];
    char* hw = hb[0] + ((col >> 5) << 10) + (((col >> 3) & 3) << 8) + (lq << 6) + ((col & 7) << 1);
    #pragma unroll
    for (int j = 0; j < 4; ++j) *(bf16*)(hw + j * 16) = (bf16)h[i][j];
  }
  __syncthreads();

  const char* gxb = (const char*)gx + (size_t)bg * SLAB;
  uint4 gc[6];
  #pragma unroll
  for (int r = 0; r < 3; ++r)
    #pragma unroll
    for (int p = 0; p < 2; ++p)
      gc[r * 2 + p] = *(const uint4*)(gxb + r * 8192 + w * 2048 + lq * 512 + lr * 32 + p * 16);

  for (int t = 0; t < TC; ++t) {
    int cur = t & 1;
    const char* hc = hb[cur] + lq * 256 + lr * 16;
    char* hn = hb[cur ^ 1];
    bf16x8 Ah[8];
    #pragma unroll
    for (int kk = 0; kk < 8; ++kk) Ah[kk] = *(const bf16x8*)(hc + kk * 1024);
    uint4 gn[6];
    bool pf = (t + 1 < TC);
    if (pf) {
      const char* sl = gxb + (size_t)(t + 1) * (64 * SLAB);
      #pragma unroll
      for (int r = 0; r < 3; ++r)
        #pragma unroll
        for (int p = 0; p < 2; ++p)
          gn[r * 2 + p] = *(const uint4*)(sl + r * 8192 + w * 2048 + lq * 512 + lr * 32 + p * 16);
    }
    const uint32_t* gcw = (const uint32_t*)gc;
    #pragma unroll
    for (int i = 0; i < 4; ++i) {
      f32x4 aR, aN, aA;
      #pragma unroll
      for (int e = 0; e < 4; ++e) { aR[e] = 0.f; aN[e] = bN[i]; aA[e] = 0.f; }
      #pragma unroll
      for (int kk = 0; kk < 8; ++kk) {
        aR = __builtin_amdgcn_mfma_f32_16x16x32_bf16(Ah[kk], wR[i][kk], aR, 0, 0, 0);
        aN = __builtin_amdgcn_mfma_f32_16x16x32_bf16(Ah[kk], wN[i][kk], aN, 0, 0, 0);
        aA = __builtin_amdgcn_mfma_f32_16x16x32_bf16(Ah[kk], wC[i][kk], aA, 0, 0, 0);
      }
      // gx words: region r, uint4 #(r*2 + (i>>1)), words (i&1)*2 + {0,1}
      uint32_t r0 = gcw[(0 * 2 + (i >> 1)) * 4 + (i & 1) * 2], r1 = gcw[(0 * 2 + (i >> 1)) * 4 + (i & 1) * 2 + 1];
      uint32_t n0 = gcw[(1 * 2 + (i >> 1)) * 4 + (i & 1) * 2], n1 = gcw[(1 * 2 + (i >> 1)) * 4 + (i & 1) * 2 + 1];
      uint32_t a0 = gcw[(2 * 2 + (i >> 1)) * 4 + (i & 1) * 2], a1 = gcw[(2 * 2 + (i >> 1)) * 4 + (i & 1) * 2 + 1];
      float irj[4] = { bflo(r0), bfhi(r0), bflo(r1), bfhi(r1) };
      float inj[4] = { bflo(n0), bfhi(n0), bflo(n1), bfhi(n1) };
      float aij[4] = { bflo(a0), bfhi(a0), bflo(a1), bfhi(a1) };
      int col = (w * 4 + i) * 16 + lr;
      #pragma unroll
      for (int j = 0; j < 4; ++j) {
        float rg = sigm(irj[j] + aR[j]);
        float xx = inj[j] + rg * aN[j];
        xx = fminf(fmaxf(xx, -15.f), 15.f);
        float e2 = exp2f(-2.885390081777927f * xx);
        float ng = (1.f - e2) * __builtin_amdgcn_rcpf(1.f + e2);
        float ig = sigm(aij[j] + aA[j]);
        float hy = ng + ig * (h[i][j] - ng);
        h[i][j] = hy;
        out[((size_t)(b0 + lq * 4 + j) * Tsz + (t0 + t)) * Hsz + col] = hy;
      }
      char* hw = hn + ((col >> 5) << 10) + (((col >> 3) & 3) << 8) + (lq << 6) + ((col & 7) << 1);
      #pragma unroll
      for (int j = 0; j < 4; ++j) *(bf16*)(hw + j * 16) = (bf16)h[i][j];
    }
    if (pf) {
      #pragma unroll
      for (int q = 0; q < 6; ++q) gc[q] = gn[q];
    }
    // h writes visible to block; do NOT drain vmcnt (out-stores/gx-prefetch fly on)
    asm volatile("s_waitcnt lgkmcnt(0)" ::: "memory");
    __builtin_amdgcn_s_barrier();
    __builtin_amdgcn_sched_barrier(0);
  }
  #pragma unroll
  for (int i = 0; i < 4; ++i) {
    int col = (w * 4 + i) * 16 + lr;
    #pragma unroll
    for (int j = 0; j < 4; ++j)
      hstate[(size_t)(b0 + lq * 4 + j) * Hsz + col] = h[i][j];
  }
}

extern "C" void kernel_launch(void* const* d_in, const int* in_sizes, int n_in,
                              void* d_out, int out_size, void* d_ws, size_t ws_size,
                              hipStream_t stream) {
  (void)in_sizes; (void)n_in; (void)out_size;
  const float* x  = (const float*)d_in[0];
  const float* Wx = (const float*)d_in[1];
  const float* bx = (const float*)d_in[2];
  const float* Wh = (const float*)d_in[3];
  const float* bh = (const float*)d_in[4];
  const float* Wa = (const float*)d_in[5];
  const float* ba = (const float*)d_in[6];
  float* out = (float*)d_out;
  char* ws = (char*)d_ws;

  bf16* wxf = (bf16*)ws;                        // 48 tiles * 8KB = 393216 B (R,N,Wp)
  bf16* whf = (bf16*)(ws + 393216);             // 262144 B (R + N)
  bf16* wcf = (bf16*)(ws + 655360);             // 131072 B
  float* c0 = (float*)(ws + 786432);            // 1024 B
  float* hstate = (float*)(ws + 1048576);       // 1 MB
  bf16* gxbuf = (bf16*)(ws + 2097152);

  size_t avail = (ws_size > 2097152) ? ws_size - 2097152 : 0;
  size_t per_t = (size_t)64 * SLAB;             // 1.5 MB per timestep
  long tcl = (long)(avail / per_t);
  int TC = (tcl > Tsz) ? Tsz : (int)tcl;
  TC &= ~63;
  if (TC < 64) TC = 64;

  k_repack<<<dim3(128), dim3(256), 0, stream>>>(Wx, Wh, wxf, whf);
  k_wc<<<dim3(256), dim3(256), 0, stream>>>(Wa, Wh, Wx, bh, bx, ba, wcf, wxf, c0);
  for (int t0 = 0; t0 < Tsz; t0 += TC) {
    int tc = Tsz - t0; if (tc > TC) tc = TC;
    k_phase1<<<dim3(64, tc / 16), dim3(512), 0, stream>>>(x, wxf, bx, bh, c0, gxbuf, t0);
    k_phase2<<<dim3(64), dim3(256), 0, stream>>>(gxbuf, whf, wcf, bh, out, hstate, t0, tc);
  }
}

// Round 6
// 2913.809 us; speedup vs baseline: 1.1591x; 1.1591x over previous
//
#include <hip/hip_runtime.h>
#include <stdint.h>
#include <stddef.h>

#define Bsz 1024
#define Tsz 512
#define Dsz 256
#define Hsz 256
#define SLAB 24576   // bytes per (t, bgroup16) slab: [r 8K][n 8K][a 8K]; tile ct: +ct*512

typedef __bf16 bf16;
typedef __attribute__((ext_vector_type(8))) __bf16 bf16x8;
typedef __attribute__((ext_vector_type(4))) float f32x4;

#define MFMA __builtin_amdgcn_mfma_f32_16x16x32_bf16

__device__ __forceinline__ float sigm(float x) {
  return __builtin_amdgcn_rcpf(1.f + exp2f(-1.4426950408889634f * x));
}
__device__ __forceinline__ float bflo(uint32_t v) {
  union { uint32_t u; float f; } c; c.u = v << 16; return c.f;
}
__device__ __forceinline__ float bfhi(uint32_t v) {
  union { uint32_t u; float f; } c; c.u = v & 0xffff0000u; return c.f;
}

// ============ repack Wx(R,N), Wh(R,N) into MFMA-fragment-major bf16 ============
// frag f=(tile,kp): elem at lane(lq,lr),e  =  W[tile*16+lr][kp*32+lq*8+e]
__global__ __launch_bounds__(256) void k_repack(
    const float* __restrict__ Wx, const float* __restrict__ Wh,
    bf16* __restrict__ wxf, bf16* __restrict__ whf) {
  int g = blockIdx.x * 256 + threadIdx.x;   // 32768 total
  int gg = g & 16383;
  int lr = gg & 15, lq = (gg >> 4) & 3, kp = (gg >> 6) & 7, tile = gg >> 9;
  int row = (tile < 16) ? (tile * 16 + lr) : (512 + (tile - 16) * 16 + lr);
  const float* s;
  bf16* d;
  if (g < 16384) { s = Wx + row * 256 + kp * 32 + lq * 8; d = wxf + gg * 8; }
  else           { s = Wh + row * 256 + kp * 32 + lq * 8; d = whf + gg * 8; }
  #pragma unroll
  for (int e = 0; e < 8; ++e) d[e] = (bf16)s[e];
}

// ==== Wc = Wa_h @ Wh_I ; Wp = Wa_i @ Wx_I ; c0 = ba + Wa_h@bh_I + Wa_i@bx_I ====
__global__ __launch_bounds__(256) void k_wc(
    const float* __restrict__ Wa, const float* __restrict__ Wh,
    const float* __restrict__ Wx, const float* __restrict__ bh,
    const float* __restrict__ bx, const float* __restrict__ ba,
    bf16* __restrict__ wcf, bf16* __restrict__ wxf, float* __restrict__ c0) {
  __shared__ float red[256];
  int n = blockIdx.x, k = threadIdx.x;
  float accC = 0.f, accP = 0.f;
  for (int m = 0; m < 256; ++m) {
    accC += Wa[n * 512 + 256 + m] * Wh[(256 + m) * 256 + k];
    accP += Wa[n * 512 + m]       * Wx[(256 + m) * 256 + k];
  }
  int kp = k >> 5, lq = (k >> 3) & 3, e = k & 7;
  int ti = n >> 4, lr = n & 15;
  wcf[(ti * 8 + kp) * 512 + lq * 128 + lr * 8 + e] = (bf16)accC;
  wxf[(((32 + ti) * 8) + kp) * 512 + lq * 128 + lr * 8 + e] = (bf16)accP;
  red[k] = Wa[n * 512 + 256 + k] * bh[256 + k] + Wa[n * 512 + k] * bx[256 + k];
  __syncthreads();
  for (int s = 128; s > 0; s >>= 1) {
    if (k < s) red[k] += red[k + s];
    __syncthreads();
  }
  if (k == 0) c0[n] = ba[n] + red[0];
}

// ============ phase 1: weight-RESIDENT gx precompute ============
// block = 16 batch rows x TP timesteps; 8 waves; wave w owns flat tiles {i*8+w}.
// gx[tloc][bg] slab: region*8192 + ct*512 + lq*128 + lr*8 (uint2 of 4 batch rows)
__global__ __launch_bounds__(512, 2) void k_phase1(
    const float* __restrict__ x, const bf16* __restrict__ wxf,
    const float* __restrict__ bx, const float* __restrict__ bh,
    const float* __restrict__ c0, bf16* __restrict__ gx, int t0, int TP) {
  int tid = threadIdx.x;
  int w = tid >> 6, l = tid & 63, lr = l & 15, lq = l >> 4;
  int bg = blockIdx.x, b0 = bg << 4;
  int tl0 = blockIdx.y * TP;
  int loffE = lq * 128 + lr * 8;

  bf16x8 W[6][8];
  float bias[6];
  #pragma unroll
  for (int i = 0; i < 6; ++i) {
    int ft = i * 8 + w;
    #pragma unroll
    for (int kk = 0; kk < 8; ++kk)
      W[i][kk] = *(const bf16x8*)(wxf + (size_t)(ft * 8 + kk) * 512 + loffE);
    int rgn = ft >> 4, r = (ft & 15) * 16 + lr;
    bias[i] = (rgn == 0) ? bx[r] + bh[r] : (rgn == 1) ? bx[512 + r] : c0[r];
  }
  const float* xbase = x + (size_t)(b0 + lr) * (Tsz * Dsz) + lq * 8;
  #pragma unroll 1
  for (int tt = 0; tt < TP; ++tt) {
    int tloc = tl0 + tt;
    const float* xp = xbase + (size_t)(t0 + tloc) * Dsz;
    bf16x8 A[8];
    #pragma unroll
    for (int kk = 0; kk < 8; ++kk) {
      float4 f0 = *(const float4*)(xp + kk * 32);
      float4 f1 = *(const float4*)(xp + kk * 32 + 4);
      bf16x8 a;
      a[0] = (bf16)f0.x; a[1] = (bf16)f0.y; a[2] = (bf16)f0.z; a[3] = (bf16)f0.w;
      a[4] = (bf16)f1.x; a[5] = (bf16)f1.y; a[6] = (bf16)f1.z; a[7] = (bf16)f1.w;
      A[kk] = a;
    }
    f32x4 acc[6];
    #pragma unroll
    for (int i = 0; i < 6; ++i)
      #pragma unroll
      for (int e = 0; e < 4; ++e) acc[i][e] = bias[i];
    #pragma unroll
    for (int kk = 0; kk < 8; ++kk)
      #pragma unroll
      for (int i = 0; i < 6; ++i)
        acc[i] = MFMA(A[kk], W[i][kk], acc[i], 0, 0, 0);
    char* sb = (char*)gx + ((size_t)tloc * 64 + bg) * SLAB;
    #pragma unroll
    for (int i = 0; i < 6; ++i) {
      int ft = i * 8 + w;
      union { bf16 v[4]; uint2 u; } pk;
      #pragma unroll
      for (int j = 0; j < 4; ++j) pk.v[j] = (bf16)acc[i][j];
      *(uint2*)(sb + (ft >> 4) * 8192 + (ft & 15) * 512 + loffE) = pk.u;
    }
  }
}

// ============ phase 2: scan; 8 waves x 32 cols; ALL weights register-resident ============
// wave w owns col-tiles {2w, 2w+1} in R, N, C. 192 weight VGPRs + ~60 working <= 256.
__global__ __launch_bounds__(512, 2) void k_phase2(
    const bf16* __restrict__ gx, const bf16* __restrict__ whf,
    const bf16* __restrict__ wcf, const float* __restrict__ bh,
    float* __restrict__ out, float* __restrict__ hstate, int t0, int TC) {
  __shared__ char hb[2][8192];   // h bf16 A-frag layout, double-buffered
  int tid = threadIdx.x;
  int w = tid >> 6, l = tid & 63, lr = l & 15, lq = l >> 4;
  int bg = blockIdx.x, b0 = bg << 4;
  int loffE = lq * 128 + lr * 8;

  bf16x8 wR[2][8], wN[2][8], wC[2][8];
  #pragma unroll
  for (int p = 0; p < 2; ++p)
    #pragma unroll
    for (int kk = 0; kk < 8; ++kk) {
      int ctile = 2 * w + p;
      wR[p][kk] = *(const bf16x8*)(whf + (size_t)(ctile * 8 + kk) * 512 + loffE);
      wN[p][kk] = *(const bf16x8*)(whf + (size_t)((16 + ctile) * 8 + kk) * 512 + loffE);
      wC[p][kk] = *(const bf16x8*)(wcf + (size_t)(ctile * 8 + kk) * 512 + loffE);
    }
  float bN[2];
  bN[0] = bh[512 + (2 * w + 0) * 16 + lr];
  bN[1] = bh[512 + (2 * w + 1) * 16 + lr];

  float h[2][4];
  #pragma unroll
  for (int p = 0; p < 2; ++p) {
    int col = (2 * w + p) * 16 + lr;
    #pragma unroll
    for (int j = 0; j < 4; ++j)
      h[p][j] = (t0 == 0) ? 0.f : hstate[(size_t)(b0 + 4 * lq + j) * Hsz + col];
    int lqp = (col >> 3) & 3, e2 = (col & 7) * 2;
    char* hw = hb[0] + w * 1024 + lqp * 256 + lq * 64 + e2;
    #pragma unroll
    for (int j = 0; j < 4; ++j) *(bf16*)(hw + j * 16) = (bf16)h[p][j];
  }
  __syncthreads();

  const char* gxb = (const char*)gx + (size_t)bg * SLAB;
  const size_t tstride = (size_t)64 * SLAB;
  uint2 gR[2], gN[2], gA[2];
  #pragma unroll
  for (int p = 0; p < 2; ++p) {
    int toff = (2 * w + p) * 512 + loffE;
    gR[p] = *(const uint2*)(gxb + toff);
    gN[p] = *(const uint2*)(gxb + 8192 + toff);
    gA[p] = *(const uint2*)(gxb + 16384 + toff);
  }

  #pragma unroll 1
  for (int t = 0; t < TC; ++t) {
    int cur = t & 1, nxt = cur ^ 1;
    const char* hc = hb[cur] + lq * 256 + lr * 16;
    bf16x8 AhA[4], AhB[4];
    #pragma unroll
    for (int kk = 0; kk < 4; ++kk) AhA[kk] = *(const bf16x8*)(hc + kk * 1024);
    #pragma unroll
    for (int kk = 0; kk < 4; ++kk) AhB[kk] = *(const bf16x8*)(hc + (4 + kk) * 1024);
    f32x4 aR[2], aN[2], aA[2];
    #pragma unroll
    for (int p = 0; p < 2; ++p)
      #pragma unroll
      for (int e = 0; e < 4; ++e) { aR[p][e] = 0.f; aN[p][e] = bN[p]; aA[p][e] = 0.f; }
    #pragma unroll
    for (int kk = 0; kk < 4; ++kk) {
      aR[0] = MFMA(AhA[kk], wR[0][kk], aR[0], 0, 0, 0);
      aR[1] = MFMA(AhA[kk], wR[1][kk], aR[1], 0, 0, 0);
      aN[0] = MFMA(AhA[kk], wN[0][kk], aN[0], 0, 0, 0);
      aN[1] = MFMA(AhA[kk], wN[1][kk], aN[1], 0, 0, 0);
      aA[0] = MFMA(AhA[kk], wC[0][kk], aA[0], 0, 0, 0);
      aA[1] = MFMA(AhA[kk], wC[1][kk], aA[1], 0, 0, 0);
    }
    #pragma unroll
    for (int kk = 0; kk < 4; ++kk) {
      aR[0] = MFMA(AhB[kk], wR[0][kk + 4], aR[0], 0, 0, 0);
      aR[1] = MFMA(AhB[kk], wR[1][kk + 4], aR[1], 0, 0, 0);
      aN[0] = MFMA(AhB[kk], wN[0][kk + 4], aN[0], 0, 0, 0);
      aN[1] = MFMA(AhB[kk], wN[1][kk + 4], aN[1], 0, 0, 0);
      aA[0] = MFMA(AhB[kk], wC[0][kk + 4], aA[0], 0, 0, 0);
      aA[1] = MFMA(AhB[kk], wC[1][kk + 4], aA[1], 0, 0, 0);
    }
    // ---- gates in registers; write h (LDS) then out (global) ----
    #pragma unroll
    for (int p = 0; p < 2; ++p) {
      float irj[4] = { bflo(gR[p].x), bfhi(gR[p].x), bflo(gR[p].y), bfhi(gR[p].y) };
      float inj[4] = { bflo(gN[p].x), bfhi(gN[p].x), bflo(gN[p].y), bfhi(gN[p].y) };
      float aij[4] = { bflo(gA[p].x), bfhi(gA[p].x), bflo(gA[p].y), bfhi(gA[p].y) };
      int col = (2 * w + p) * 16 + lr;
      #pragma unroll
      for (int j = 0; j < 4; ++j) {
        float rg = sigm(irj[j] + aR[p][j]);
        float xx = inj[j] + rg * aN[p][j];
        xx = fminf(fmaxf(xx, -15.f), 15.f);
        float e2 = exp2f(-2.885390081777927f * xx);
        float ng = (1.f - e2) * __builtin_amdgcn_rcpf(1.f + e2);
        float ig = sigm(aij[j] + aA[p][j]);
        h[p][j] = ng + ig * (h[p][j] - ng);
      }
      int lqp = (col >> 3) & 3, e2b = (col & 7) * 2;
      char* hw = hb[nxt] + w * 1024 + lqp * 256 + lq * 64 + e2b;
      #pragma unroll
      for (int j = 0; j < 4; ++j) *(bf16*)(hw + j * 16) = (bf16)h[p][j];
      #pragma unroll
      for (int j = 0; j < 4; ++j)
        out[(size_t)(b0 + 4 * lq + j) * (Tsz * Hsz) + (size_t)(t0 + t) * Hsz + col] = h[p][j];
    }
    // ---- issue next step's gx loads into same regs (WAR after gate reads) ----
    if (t + 1 < TC) {
      const char* sl = gxb + (size_t)(t + 1) * tstride;
      #pragma unroll
      for (int p = 0; p < 2; ++p) {
        int toff = (2 * w + p) * 512 + loffE;
        gR[p] = *(const uint2*)(sl + toff);
        gN[p] = *(const uint2*)(sl + 8192 + toff);
        gA[p] = *(const uint2*)(sl + 16384 + toff);
      }
    }
    asm volatile("s_waitcnt lgkmcnt(0)" ::: "memory");
    __builtin_amdgcn_s_barrier();
    __builtin_amdgcn_sched_barrier(0);
  }
  #pragma unroll
  for (int p = 0; p < 2; ++p) {
    int col = (2 * w + p) * 16 + lr;
    #pragma unroll
    for (int j = 0; j < 4; ++j)
      hstate[(size_t)(b0 + 4 * lq + j) * Hsz + col] = h[p][j];
  }
}

extern "C" void kernel_launch(void* const* d_in, const int* in_sizes, int n_in,
                              void* d_out, int out_size, void* d_ws, size_t ws_size,
                              hipStream_t stream) {
  (void)in_sizes; (void)n_in; (void)out_size;
  const float* x  = (const float*)d_in[0];
  const float* Wx = (const float*)d_in[1];
  const float* bx = (const float*)d_in[2];
  const float* Wh = (const float*)d_in[3];
  const float* bh = (const float*)d_in[4];
  const float* Wa = (const float*)d_in[5];
  const float* ba = (const float*)d_in[6];
  float* out = (float*)d_out;
  char* ws = (char*)d_ws;

  bf16* wxf = (bf16*)ws;                        // 48 tiles * 8KB = 393216 B (R,N,Wp)
  bf16* whf = (bf16*)(ws + 393216);             // 262144 B (R tiles 0..15, N tiles 16..31)
  bf16* wcf = (bf16*)(ws + 655360);             // 131072 B
  float* c0 = (float*)(ws + 786432);            // 1024 B
  float* hstate = (float*)(ws + 1048576);       // 1 MB
  bf16* gxbuf = (bf16*)(ws + 2097152);

  size_t avail = (ws_size > 2097152) ? ws_size - 2097152 : 0;
  size_t per_t = (size_t)64 * SLAB;             // 1.5 MB per timestep
  long tcl = (long)(avail / per_t);
  int TC = (tcl > Tsz) ? Tsz : (int)tcl;
  TC &= ~63;
  if (TC < 64) TC = 64;

  k_repack<<<dim3(128), dim3(256), 0, stream>>>(Wx, Wh, wxf, whf);
  k_wc<<<dim3(256), dim3(256), 0, stream>>>(Wa, Wh, Wx, bh, bx, ba, wcf, wxf, c0);
  for (int t0 = 0; t0 < Tsz; t0 += TC) {
    int tc = Tsz - t0; if (tc > TC) tc = TC;
    int TP = (tc % 128 == 0) ? 128 : 64;
    k_phase1<<<dim3(64, tc / TP), dim3(512), 0, stream>>>(x, wxf, bx, bh, c0, gxbuf, t0, TP);
    k_phase2<<<dim3(64), dim3(512), 0, stream>>>(gxbuf, whf, wcf, bh, out, hstate, t0, tc);
  }
}